// Round 4
// baseline (2055.899 us; speedup 1.0000x reference)
//
#include <hip/hip_runtime.h>
#include <hip/hip_fp16.h>

// Problem constants
#define BB 128
#define SS 512
#define EE 16
#define HH 256
#define G3 768
#define VV 256

typedef _Float16 half8 __attribute__((ext_vector_type(8)));
typedef _Float16 half4_t __attribute__((ext_vector_type(4)));
typedef float f32x4 __attribute__((ext_vector_type(4)));

// 16B global->LDS DMA. LDS dest is wave-uniform base (HW adds lane*16);
// global src is per-lane. Casts go through integers to satisfy addrspace
// rules (generic LDS ptr keeps the byte offset in its low 32 bits).
__device__ __forceinline__ void dma16(const void* g, const void* l) {
  __builtin_amdgcn_global_load_lds(
      (const __attribute__((address_space(1))) unsigned int*)(unsigned long long)g,
      (__attribute__((address_space(3))) unsigned int*)(unsigned int)(unsigned long long)l,
      16, 0, 0);
}

// ---------------------------------------------------------------------------
// P: swizzle W_hh [256][768] and W_out [256][256] (fp32, row=K, col=N) into
// fp16 MFMA B-fragment order: flat idx = ((n_tile*8 + k_tile)*64 + lane)*8 + j
// ---------------------------------------------------------------------------
__global__ __launch_bounds__(256) void swizzle_weights(
    const float* __restrict__ Whh, const float* __restrict__ Wout,
    _Float16* __restrict__ whh_swz, _Float16* __restrict__ wout_swz) {
  int t = blockIdx.x * 256 + threadIdx.x;
  if (t < 48 * 8 * 64 * 8) {  // 196608 elements of W_hh
    int j = t & 7, L = (t >> 3) & 63, k = (t >> 9) & 7, n = t >> 12;
    int row = k * 32 + (L >> 4) * 8 + j;
    int col = n * 16 + (L & 15);
    whh_swz[t] = (_Float16)Whh[row * G3 + col];
  }
  if (t < 16 * 8 * 64 * 8) {  // 65536 elements of W_out
    int j = t & 7, L = (t >> 3) & 63, k = (t >> 9) & 7, n = t >> 12;
    int row = k * 32 + (L >> 4) * 8 + j;
    int col = n * 16 + (L & 15);
    wout_swz[t] = (_Float16)Wout[row * VV + col];
  }
}

// ---------------------------------------------------------------------------
// K1: gi = emb[x] @ W_ih + b_ih (+ b_hh folded for r,z gates), written fp16 in
// the swizzled per-(batch-group, t) layout K2's lanes read with 8B loads.
// ---------------------------------------------------------------------------
__global__ __launch_bounds__(256) void gi_kernel(
    const int* __restrict__ x, const float* __restrict__ embed,
    const float* __restrict__ W_ih, const float* __restrict__ b_ih,
    const float* __restrict__ b_hh, _Float16* __restrict__ gi_swz) {
  int gid = blockIdx.x;          // 0..1023
  int bg = gid >> 7;             // batch group 0..7
  int t0 = (gid & 127) * 4;      // 4 timesteps per block
  int tid = threadIdx.x;

  __shared__ __align__(16) float s_wih[EE * G3];      // 48 KB
  __shared__ __align__(16) float s_bias[G3];          // 3 KB
  __shared__ __align__(16) float s_emb16[4][16][EE];  // 4 KB
  __shared__ int s_x[4][16];

  for (int i = tid; i < EE * G3; i += 256) s_wih[i] = W_ih[i];
  for (int i = tid; i < G3; i += 256)
    s_bias[i] = b_ih[i] + (i < 512 ? b_hh[i] : 0.0f);  // fold b_hh for r,z only
  if (tid < 64) {
    int tt = tid >> 4, m = tid & 15;
    s_x[tt][m] = x[(bg * 16 + m) * SS + t0 + tt];
  }
  __syncthreads();
  for (int i = tid; i < 4 * 16 * EE; i += 256) {
    int tt = i >> 8, m = (i >> 4) & 15, e = i & 15;
    s_emb16[tt][m][e] = embed[s_x[tt][m] * EE + e];
  }
  __syncthreads();

  for (int cch = 0; cch < 3; cch++) {
    int gc = cch * 256 + tid;  // gate column
    float w[EE];
#pragma unroll
    for (int e = 0; e < EE; e++) w[e] = s_wih[e * G3 + gc];
    float bias = s_bias[gc];
    int wi = (gc >> 4) & 15, cc = gc & 15;
    int tilebase = (cch * 16 + wi) * 64;
    for (int tt = 0; tt < 4; tt++) {
      size_t gbase = (size_t)(bg * 512 + t0 + tt) * 12288;
#pragma unroll
      for (int mq = 0; mq < 4; mq++) {
        half4_t v;
#pragma unroll
        for (int r = 0; r < 4; r++) {
          int m = mq * 4 + r;
          float acc = bias;
#pragma unroll
          for (int e = 0; e < EE; e++) acc += s_emb16[tt][m][e] * w[e];
          v[r] = (_Float16)acc;
        }
        *(half4_t*)(gi_swz + gbase + (size_t)((tilebase + mq * 16 + cc) * 4)) = v;
      }
    }
  }
}

// ---------------------------------------------------------------------------
// K2: GRU recurrence. 8 blocks x 1024 threads — EXACT R0 structure (the
// measured best: 1380us; R7/R8/R9 restructures all regressed) except:
//
//  R10a: gi arrives via global_load_lds DMA, 2 steps ahead, into a 3-slot
//        24KB LDS ring (zero VGPR cost). R0 exposed ~500-900cy/step of gi
//        load latency (FETCH shows ~50% of the 100MB gi stream misses L3);
//        DMA issued at step t for step t+2 has a full step (~6000cy) of
//        cover. Consumption = 3 conflict-free ds_read_b64.
//  R10b: __syncthreads -> "s_waitcnt vmcnt(N) lgkmcnt(0)" + s_barrier.
//        __syncthreads drains vmcnt(0): the 4 scattered 2B h_seq stores
//        (~300-500cy ack) every step, and would kill the DMA pipeline.
//        Counted N = this step's stores(4)+DMA issues(n): waves 0-7 issue
//        n=2 DMA/step -> vmcnt(6); waves 8-15 n=1 -> vmcnt(5). At the
//        barrier every wave has ensured ITS step-t+1 DMAs and step-t-1
//        stores completed; step-t stores and step-t+2 DMAs stay in flight.
//
// Register pressure unchanged vs R0 (gi values occupy the same 3 half4
// regs, now ds_read-fed; DMA needs no data regs). Spill tripwire:
// WRITE_SIZE must stay exactly 32768KB — scratch VMEM ops would corrupt
// the vmcnt accounting.
// LDS: 16.9KB h double-buffer + 72KB gi ring = 89.5KB (1 block/CU).
// ---------------------------------------------------------------------------
__global__ void __launch_bounds__(1024)
__attribute__((amdgpu_waves_per_eu(4, 4)))
gru_kernel(
    const _Float16* __restrict__ gi_swz, const _Float16* __restrict__ whh_swz,
    const float* __restrict__ b_hh, _Float16* __restrict__ h_seq) {
  int bg = blockIdx.x;  // 0..7
  int tid = threadIdx.x;
  int w = tid >> 6, L = tid & 63;
  int q = L >> 4, c = L & 15;

  __shared__ __align__(16) _Float16 s_h[2][16][264];   // 16.9 KB
  __shared__ __align__(16) _Float16 s_gi[3][12288];    // 72 KB ring

  // All three B fragments for this wave's column tile, in registers.
  half8 wR[8], wZ[8], wN[8];
#pragma unroll
  for (int k = 0; k < 8; k++) {
    wR[k] = *(const half8*)(whh_swz + (((size_t)((0 * 16 + w) * 8 + k) * 64 + L) * 8));
    wZ[k] = *(const half8*)(whh_swz + (((size_t)((1 * 16 + w) * 8 + k) * 64 + L) * 8));
    wN[k] = *(const half8*)(whh_swz + (((size_t)((2 * 16 + w) * 8 + k) * 64 + L) * 8));
  }
  // n-gate hidden bias (multiplied by r inside the step)
  float bhn = b_hh[512 + w * 16 + c];

  // zero both h buffers (h0 = 0): 8448 halves = 4224 uints
  for (int idx = tid; idx < (2 * 16 * 264) / 2; idx += 1024)
    ((unsigned int*)s_h)[idx] = 0u;

  // Prologue DMA: fill slot0 (t=0) and slot1 (t=1). Per step a block moves
  // 24KB = 24 chunks of 1024B; wave w takes chunk w, and chunk 16+w if w<8.
  {
    const char* g0 = (const char*)gi_swz + (size_t)(bg * 512) * 24576;
    const char* g1 = g0 + 24576;
    dma16(g0 + w * 1024 + L * 16, (const char*)s_gi[0] + w * 1024);
    if (w < 8) dma16(g0 + (16 + w) * 1024 + L * 16, (const char*)s_gi[0] + (16 + w) * 1024);
    dma16(g1 + w * 1024 + L * 16, (const char*)s_gi[1] + w * 1024);
    if (w < 8) dma16(g1 + (16 + w) * 1024 + L * 16, (const char*)s_gi[1] + (16 + w) * 1024);
  }
  // slot0 must be complete (slot1's n loads may stay in flight) + h zeroed.
  if (w < 8) asm volatile("s_waitcnt vmcnt(2) lgkmcnt(0)" ::: "memory");
  else       asm volatile("s_waitcnt vmcnt(1) lgkmcnt(0)" ::: "memory");
  __builtin_amdgcn_s_barrier();

  int col = w * 16 + c;
  // h_seq flat offset (halves) for (batch row bg*16 + q*4, t=0, col)
  unsigned hoff = (unsigned)(bg * 16 + q * 4) * (SS * HH) + (unsigned)col;
  // global byte base of the gi block for step t+2 (DMA target stream)
  const char* gsrc = (const char*)gi_swz + (size_t)(bg * 512 + 2) * 24576;

  const _Float16* hsrc = &s_h[0][0][0];
  _Float16* hdst = &s_h[1][0][0];
  const _Float16* g0 = s_gi[0];  // slot for t
  const _Float16* g1 = s_gi[1];  // slot for t+1
  const _Float16* g2 = s_gi[2];  // slot being filled for t+2
  const int aoff = c * 264 + q * 8;             // av base (halves)
  const int woff = (q * 4) * 264 + col;         // h-write base (halves)
  const int gioff = (w * 64 + L) * 4;           // gi lane offset (halves)

#pragma unroll 1
  for (int t = 0; t < SS; t++) {
    // gate inputs from the LDS ring (conflict-free ds_read_b64 x3)
    half4_t giR = *(const half4_t*)(g0 + gioff);
    half4_t giZ = *(const half4_t*)(g0 + gioff + 4096);
    half4_t giN = *(const half4_t*)(g0 + gioff + 8192);

    f32x4 aR = {0.f, 0.f, 0.f, 0.f}, aZ = aR, aN = aR;
#pragma unroll
    for (int k = 0; k < 8; k++) {
      half8 av = *(const half8*)(hsrc + aoff + k * 32);  // A[m=c][k*32+q*8+j]
      aR = __builtin_amdgcn_mfma_f32_16x16x32_f16(av, wR[k], aR, 0, 0, 0);
      aZ = __builtin_amdgcn_mfma_f32_16x16x32_f16(av, wZ[k], aZ, 0, 0, 0);
      aN = __builtin_amdgcn_mfma_f32_16x16x32_f16(av, wN[k], aN, 0, 0, 0);
    }

#pragma unroll
    for (int r = 0; r < 4; r++) {
      float hpv = (float)hsrc[(q * 4 + r) * 264 + col];  // lane's own h_{t-1}
      float rg = aR[r] + (float)giR[r];
      rg = 1.f / (1.f + __expf(-rg));
      float zg = aZ[r] + (float)giZ[r];
      zg = 1.f / (1.f + __expf(-zg));
      float ng = (float)giN[r] + rg * (aN[r] + bhn);
      ng = 2.f / (1.f + __expf(-2.f * ng)) - 1.f;  // tanh
      float hn = (1.f - zg) * ng + zg * hpv;
      _Float16 h16 = (_Float16)hn;
      hdst[woff + r * 264] = h16;
      h_seq[(size_t)(hoff + (unsigned)r * 131072u)] = h16;
    }

    // DMA issue for step t+2 into slot g2 (t>=510 reads past gi into the
    // weight regions of the same workspace — valid memory, values unused;
    // unconditional issue keeps per-wave vmcnt counts uniform).
    dma16(gsrc + w * 1024 + L * 16, (const char*)g2 + w * 1024);
    if (w < 8) dma16(gsrc + (16 + w) * 1024 + L * 16, (const char*)g2 + (16 + w) * 1024);
    gsrc += 24576;

    // Counted-vmcnt barrier: completes step-t+1 DMAs and step-t-1 stores;
    // leaves step-t stores (4) + step-t+2 DMAs (n) in flight.
    if (w < 8) asm volatile("s_waitcnt vmcnt(6) lgkmcnt(0)" ::: "memory");
    else       asm volatile("s_waitcnt vmcnt(5) lgkmcnt(0)" ::: "memory");
    __builtin_amdgcn_s_barrier();

    const _Float16* tp = hsrc; hsrc = hdst; hdst = (_Float16*)tp;
    const _Float16* tg = g0; g0 = g1; g1 = g2; g2 = tg;
    hoff += (unsigned)HH;
  }
}

// ---------------------------------------------------------------------------
// K3: out = h_seq @ W_out + b_out via fp16 MFMA. 1024 blocks x 256 threads;
// block handles 64 bt-rows (wave w -> rows w*16..+16), full N=256 (16 tiles).
// Static LDS = 33 KB.  Output written fp32.
// ---------------------------------------------------------------------------
__global__ __launch_bounds__(256) void out_kernel(
    const _Float16* __restrict__ h_seq, const _Float16* __restrict__ wout_swz,
    const float* __restrict__ b_out, float* __restrict__ out) {
  int blk = blockIdx.x;
  int tid = threadIdx.x;
  int w = tid >> 6, L = tid & 63, q = L >> 4, c = L & 15;

  __shared__ __align__(16) _Float16 s_a[64 * 264];  // 33 KB

  const _Float16* src = h_seq + (size_t)blk * 64 * 256;
  for (int idx = tid; idx < (64 * 256) / 8; idx += 256) {
    int row = idx >> 5, kk = (idx & 31) * 8;
    *(half8*)(s_a + row * 264 + kk) = *(const half8*)(src + row * 256 + kk);
  }
  __syncthreads();

  half8 a[8];
#pragma unroll
  for (int k = 0; k < 8; k++)
    a[k] = *(const half8*)(s_a + (w * 16 + c) * 264 + k * 32 + q * 8);

  f32x4 acc[16];
#pragma unroll
  for (int n = 0; n < 16; n++) {
    f32x4 z = {0.f, 0.f, 0.f, 0.f};
    acc[n] = z;
#pragma unroll
    for (int k = 0; k < 8; k++) {
      half8 b = *(const half8*)(wout_swz + ((size_t)(n * 8 + k) * 64 + L) * 8);
      acc[n] = __builtin_amdgcn_mfma_f32_16x16x32_f16(a[k], b, acc[n], 0, 0, 0);
    }
  }
#pragma unroll
  for (int n = 0; n < 16; n++) {
    int v = n * 16 + c;
    float bo = b_out[v];
#pragma unroll
    for (int r = 0; r < 4; r++) {
      int bt = blk * 64 + w * 16 + q * 4 + r;
      out[(size_t)bt * 256 + v] = acc[n][r] + bo;
    }
  }
}

// ---------------------------------------------------------------------------
extern "C" void kernel_launch(void* const* d_in, const int* in_sizes, int n_in,
                              void* d_out, int out_size, void* d_ws, size_t ws_size,
                              hipStream_t stream) {
  const int*   x    = (const int*)d_in[0];
  const float* emb  = (const float*)d_in[1];
  const float* Wih  = (const float*)d_in[2];
  const float* bih  = (const float*)d_in[3];
  const float* Whh  = (const float*)d_in[4];
  const float* bhh  = (const float*)d_in[5];
  const float* Wout = (const float*)d_in[6];
  const float* bout = (const float*)d_in[7];

  char* ws = (char*)d_ws;
  // ws layout (134,742,016 B total):
  //   gi_swz   : 128*512*768 fp16 = 100,663,296 B
  //   whh_swz  : 196608 fp16      =     393,216 B
  //   wout_swz : 65536 fp16       =     131,072 B
  //   h_seq    : 128*512*256 fp16 =  33,554,432 B
  _Float16* gi_swz   = (_Float16*)(ws);
  _Float16* whh_swz  = (_Float16*)(ws + 100663296);
  _Float16* wout_swz = (_Float16*)(ws + 100663296 + 393216);
  _Float16* h_seq    = (_Float16*)(ws + 100663296 + 393216 + 131072);

  swizzle_weights<<<768, 256, 0, stream>>>(Whh, Wout, whh_swz, wout_swz);
  gi_kernel<<<1024, 256, 0, stream>>>(x, emb, Wih, bih, bhh, gi_swz);
  gru_kernel<<<8, 1024, 0, stream>>>(gi_swz, whh_swz, bhh, h_seq);
  out_kernel<<<1024, 256, 0, stream>>>(h_seq, wout_swz, bout, (float*)d_out);
}

// Round 5
// 1397.385 us; speedup vs baseline: 1.4712x; 1.4712x over previous
//
#include <hip/hip_runtime.h>
#include <hip/hip_fp16.h>

// Problem constants
#define BB 128
#define SS 512
#define EE 16
#define HH 256
#define G3 768
#define VV 256

typedef _Float16 half8 __attribute__((ext_vector_type(8)));
typedef _Float16 half4_t __attribute__((ext_vector_type(4)));
typedef float f32x4 __attribute__((ext_vector_type(4)));

// ---------------------------------------------------------------------------
// P: swizzle W_hh [256][768] and W_out [256][256] (fp32, row=K, col=N) into
// fp16 MFMA B-fragment order: flat idx = ((n_tile*8 + k_tile)*64 + lane)*8 + j
//   = n*4096 + k*512 + L*8 + j
// holding W[k_tile*32 + (lane>>4)*8 + j][n_tile*16 + (lane&15)].
// ---------------------------------------------------------------------------
__global__ __launch_bounds__(256) void swizzle_weights(
    const float* __restrict__ Whh, const float* __restrict__ Wout,
    _Float16* __restrict__ whh_swz, _Float16* __restrict__ wout_swz) {
  int t = blockIdx.x * 256 + threadIdx.x;
  if (t < 48 * 8 * 64 * 8) {  // 196608 elements of W_hh
    int j = t & 7, L = (t >> 3) & 63, k = (t >> 9) & 7, n = t >> 12;
    int row = k * 32 + (L >> 4) * 8 + j;
    int col = n * 16 + (L & 15);
    whh_swz[t] = (_Float16)Whh[row * G3 + col];
  }
  if (t < 16 * 8 * 64 * 8) {  // 65536 elements of W_out
    int j = t & 7, L = (t >> 3) & 63, k = (t >> 9) & 7, n = t >> 12;
    int row = k * 32 + (L >> 4) * 8 + j;
    int col = n * 16 + (L & 15);
    wout_swz[t] = (_Float16)Wout[row * VV + col];
  }
}

// ---------------------------------------------------------------------------
// K1: gi = emb[x] @ W_ih + b_ih (+ b_hh folded for r,z gates), written fp16 in
// the swizzled per-(batch-group, t) layout K2's lanes read with 8B loads.
// ---------------------------------------------------------------------------
__global__ __launch_bounds__(256) void gi_kernel(
    const int* __restrict__ x, const float* __restrict__ embed,
    const float* __restrict__ W_ih, const float* __restrict__ b_ih,
    const float* __restrict__ b_hh, _Float16* __restrict__ gi_swz) {
  int gid = blockIdx.x;          // 0..1023
  int bg = gid >> 7;             // batch group 0..7
  int t0 = (gid & 127) * 4;      // 4 timesteps per block
  int tid = threadIdx.x;

  __shared__ __align__(16) float s_wih[EE * G3];      // 48 KB
  __shared__ __align__(16) float s_bias[G3];          // 3 KB
  __shared__ __align__(16) float s_emb16[4][16][EE];  // 4 KB
  __shared__ int s_x[4][16];

  for (int i = tid; i < EE * G3; i += 256) s_wih[i] = W_ih[i];
  for (int i = tid; i < G3; i += 256)
    s_bias[i] = b_ih[i] + (i < 512 ? b_hh[i] : 0.0f);  // fold b_hh for r,z only
  if (tid < 64) {
    int tt = tid >> 4, m = tid & 15;
    s_x[tt][m] = x[(bg * 16 + m) * SS + t0 + tt];
  }
  __syncthreads();
  for (int i = tid; i < 4 * 16 * EE; i += 256) {
    int tt = i >> 8, m = (i >> 4) & 15, e = i & 15;
    s_emb16[tt][m][e] = embed[s_x[tt][m] * EE + e];
  }
  __syncthreads();

  for (int cch = 0; cch < 3; cch++) {
    int gc = cch * 256 + tid;  // gate column
    float w[EE];
#pragma unroll
    for (int e = 0; e < EE; e++) w[e] = s_wih[e * G3 + gc];
    float bias = s_bias[gc];
    int wi = (gc >> 4) & 15, cc = gc & 15;
    int tilebase = (cch * 16 + wi) * 64;
    for (int tt = 0; tt < 4; tt++) {
      size_t gbase = (size_t)(bg * 512 + t0 + tt) * 12288;
#pragma unroll
      for (int mq = 0; mq < 4; mq++) {
        half4_t v;
#pragma unroll
        for (int r = 0; r < 4; r++) {
          int m = mq * 4 + r;
          float acc = bias;
#pragma unroll
          for (int e = 0; e < EE; e++) acc += s_emb16[tt][m][e] * w[e];
          v[r] = (_Float16)acc;
        }
        *(half4_t*)(gi_swz + gbase + (size_t)((tilebase + mq * 16 + cc) * 4)) = v;
      }
    }
  }
}

// ---------------------------------------------------------------------------
// K2: GRU recurrence. 8 blocks x 1024 threads (16 waves, 4 waves/SIMD).
// Structure is EXACTLY the R0 measured-best (1380us: __syncthreads barrier,
// gi loaded at step top / added in epilogue, hp from LDS, h_seq stores in
// the epilogue) with ONE change:
//
// R11: the n-gate B-fragments (wN) move from registers to LDS.
//   Diagnosis across R7-R10: every variant kept 96 weight regs/lane, which
//   fits in NEITHER bank of the 64-arch/64-AGPR split at waves_per_eu(4,4);
//   the compiler emitted ~420 shuttle insts/wave/step (VALUBusy 68%/CU =
//   ~554 VALU insts/wave/step vs ~130 in source), and every attempted fix
//   ADDED state and tipped into loop scratch-spill (WRITE_SIZE 32768 ->
//   32864/33152/33376/33344 KB in R7/R8/R9/R10).
//   This change REDUCES the resident set: weights 96 -> 64 regs/lane
//   (wR,wZ in regs; wN = 128KB in LDS, read per-k as stride-1 conflict-free
//   ds_read_b128). Total demand ~= 64 wgt + 12 acc + 6 gi + ~25 temps = 107
//   <= 128 budget -> no shuttles, no spill. LDS pipe gains +128 b128/CU/step
//   (~+1540cy) but VALU pipe drops ~4430 -> ~1300cy; pipes overlap, so the
//   step ceiling becomes LDS ~3100-3500cy (was VALU ~4430 + stalls).
// Tripwire: WRITE_SIZE must be EXACTLY 32768 KB (any growth = spill).
// LDS: 16.9 KB h double-buffer + 128 KB wN = 144.5 KB (<160 KB/WG).
// ---------------------------------------------------------------------------
__global__ void __launch_bounds__(1024)
__attribute__((amdgpu_waves_per_eu(4, 4)))
gru_kernel(
    const _Float16* __restrict__ gi_swz, const _Float16* __restrict__ whh_swz,
    const float* __restrict__ b_hh, _Float16* __restrict__ h_seq) {
  int bg = blockIdx.x;  // 0..7
  int tid = threadIdx.x;
  int w = tid >> 6, L = tid & 63;
  int q = L >> 4, c = L & 15;

  __shared__ __align__(16) _Float16 s_h[2][16][264];  // 16.9 KB
  __shared__ __align__(16) _Float16 s_wn[65536];      // 128 KB: n-gate B-frags

  // r,z B fragments for this wave's column tile, in registers (64 VGPR).
  half8 wR[8], wZ[8];
#pragma unroll
  for (int k = 0; k < 8; k++) {
    wR[k] = *(const half8*)(whh_swz + (((size_t)((0 * 16 + w) * 8 + k) * 64 + L) * 8));
    wZ[k] = *(const half8*)(whh_swz + (((size_t)((1 * 16 + w) * 8 + k) * 64 + L) * 8));
  }
  // n-gate hidden bias (multiplied by r inside the step)
  float bhn = b_hh[512 + w * 16 + c];

  // Stage n-gate fragments into LDS: s_wn[i] = whh_swz[131072 + i]
  // (n-gate tiles start at (2*16)*8*64*8 = 131072). 8 x half8 per thread,
  // coalesced global reads, stride-1 LDS writes.
  for (int i = tid; i < 8192; i += 1024)
    *(half8*)(s_wn + i * 8) = *(const half8*)(whh_swz + 131072 + (size_t)i * 8);

  // zero both h buffers (h0 = 0): 8448 halves = 4224 uints
  for (int idx = tid; idx < (2 * 16 * 264) / 2; idx += 1024)
    ((unsigned int*)s_h)[idx] = 0u;
  __syncthreads();

  int col = w * 16 + c;
  // h_seq flat offset (halves) for (batch row bg*16 + q*4, t=0, col)
  unsigned hoff = (unsigned)(bg * 16 + q * 4) * (SS * HH) + (unsigned)col;
  // gi offset for this lane (advance by 12288/step)
  unsigned gioff = (unsigned)(bg * 512) * 12288u + (unsigned)((w * 64 + L) * 4);

  const _Float16* hsrc = &s_h[0][0][0];
  _Float16* hdst = &s_h[1][0][0];
  const int aoff = c * 264 + q * 8;             // av base (halves)
  const int woff = (q * 4) * 264 + col;         // h-write base (halves)
  const int wnoff = w * 4096 + L * 8;           // wN base for k=0 (halves)

#pragma unroll 1
  for (int t = 0; t < SS; t++) {
    // gate-input loads (global; issued early, consumed in epilogue)
    half4_t giR = *(const half4_t*)(gi_swz + gioff);
    half4_t giZ = *(const half4_t*)(gi_swz + gioff + 4096u);
    half4_t giN = *(const half4_t*)(gi_swz + gioff + 8192u);

    f32x4 aR = {0.f, 0.f, 0.f, 0.f}, aZ = aR, aN = aR;
#pragma unroll
    for (int k = 0; k < 8; k++) {
      half8 av = *(const half8*)(hsrc + aoff + k * 32);  // A[m=c][k*32+q*8+j]
      half8 wNk = *(const half8*)(s_wn + wnoff + k * 512);  // stride-1, no conflict
      aR = __builtin_amdgcn_mfma_f32_16x16x32_f16(av, wR[k], aR, 0, 0, 0);
      aZ = __builtin_amdgcn_mfma_f32_16x16x32_f16(av, wZ[k], aZ, 0, 0, 0);
      aN = __builtin_amdgcn_mfma_f32_16x16x32_f16(av, wNk, aN, 0, 0, 0);
    }

    half4_t h16v;
#pragma unroll
    for (int r = 0; r < 4; r++) {
      float hpv = (float)hsrc[(q * 4 + r) * 264 + col];  // lane's own h_{t-1}
      float rg = aR[r] + (float)giR[r];
      rg = 1.f / (1.f + __expf(-rg));
      float zg = aZ[r] + (float)giZ[r];
      zg = 1.f / (1.f + __expf(-zg));
      float ng = (float)giN[r] + rg * (aN[r] + bhn);
      ng = 2.f / (1.f + __expf(-2.f * ng)) - 1.f;  // tanh
      float hn = (1.f - zg) * ng + zg * hpv;
      _Float16 h16 = (_Float16)hn;
      h16v[r] = h16;
      hdst[woff + r * 264] = h16;
      h_seq[(size_t)(hoff + (unsigned)r * 131072u)] = h16;
    }
    __syncthreads();
    const _Float16* tp = hsrc; hsrc = hdst; hdst = (_Float16*)tp;
    hoff += (unsigned)HH;
    gioff += 12288u;
  }
}

// ---------------------------------------------------------------------------
// K3: out = h_seq @ W_out + b_out via fp16 MFMA. 1024 blocks x 256 threads;
// block handles 64 bt-rows (wave w -> rows w*16..+16), full N=256 (16 tiles).
// Static LDS = 33 KB.  Output written fp32.
// ---------------------------------------------------------------------------
__global__ __launch_bounds__(256) void out_kernel(
    const _Float16* __restrict__ h_seq, const _Float16* __restrict__ wout_swz,
    const float* __restrict__ b_out, float* __restrict__ out) {
  int blk = blockIdx.x;
  int tid = threadIdx.x;
  int w = tid >> 6, L = tid & 63, q = L >> 4, c = L & 15;

  __shared__ __align__(16) _Float16 s_a[64 * 264];  // 33 KB

  const _Float16* src = h_seq + (size_t)blk * 64 * 256;
  for (int idx = tid; idx < (64 * 256) / 8; idx += 256) {
    int row = idx >> 5, kk = (idx & 31) * 8;
    *(half8*)(s_a + row * 264 + kk) = *(const half8*)(src + row * 256 + kk);
  }
  __syncthreads();

  half8 a[8];
#pragma unroll
  for (int k = 0; k < 8; k++)
    a[k] = *(const half8*)(s_a + (w * 16 + c) * 264 + k * 32 + q * 8);

  f32x4 acc[16];
#pragma unroll
  for (int n = 0; n < 16; n++) {
    f32x4 z = {0.f, 0.f, 0.f, 0.f};
    acc[n] = z;
#pragma unroll
    for (int k = 0; k < 8; k++) {
      half8 b = *(const half8*)(wout_swz + ((size_t)(n * 8 + k) * 64 + L) * 8);
      acc[n] = __builtin_amdgcn_mfma_f32_16x16x32_f16(a[k], b, acc[n], 0, 0, 0);
    }
  }
#pragma unroll
  for (int n = 0; n < 16; n++) {
    int v = n * 16 + c;
    float bo = b_out[v];
#pragma unroll
    for (int r = 0; r < 4; r++) {
      int bt = blk * 64 + w * 16 + q * 4 + r;
      out[(size_t)bt * 256 + v] = acc[n][r] + bo;
    }
  }
}

// ---------------------------------------------------------------------------
extern "C" void kernel_launch(void* const* d_in, const int* in_sizes, int n_in,
                              void* d_out, int out_size, void* d_ws, size_t ws_size,
                              hipStream_t stream) {
  const int*   x    = (const int*)d_in[0];
  const float* emb  = (const float*)d_in[1];
  const float* Wih  = (const float*)d_in[2];
  const float* bih  = (const float*)d_in[3];
  const float* Whh  = (const float*)d_in[4];
  const float* bhh  = (const float*)d_in[5];
  const float* Wout = (const float*)d_in[6];
  const float* bout = (const float*)d_in[7];

  char* ws = (char*)d_ws;
  // ws layout (134,742,016 B total):
  //   gi_swz   : 128*512*768 fp16 = 100,663,296 B
  //   whh_swz  : 196608 fp16      =     393,216 B
  //   wout_swz : 65536 fp16       =     131,072 B
  //   h_seq    : 128*512*256 fp16 =  33,554,432 B
  _Float16* gi_swz   = (_Float16*)(ws);
  _Float16* whh_swz  = (_Float16*)(ws + 100663296);
  _Float16* wout_swz = (_Float16*)(ws + 100663296 + 393216);
  _Float16* h_seq    = (_Float16*)(ws + 100663296 + 393216 + 131072);

  swizzle_weights<<<768, 256, 0, stream>>>(Whh, Wout, whh_swz, wout_swz);
  gi_kernel<<<1024, 256, 0, stream>>>(x, emb, Wih, bih, bhh, gi_swz);
  gru_kernel<<<8, 1024, 0, stream>>>(gi_swz, whh_swz, bhh, h_seq);
  out_kernel<<<1024, 256, 0, stream>>>(h_seq, wout_swz, bout, (float*)d_out);
}

// Round 6
// 1386.666 us; speedup vs baseline: 1.4826x; 1.0077x over previous
//
#include <hip/hip_runtime.h>
#include <hip/hip_fp16.h>

// Problem constants
#define BB 128
#define SS 512
#define EE 16
#define HH 256
#define G3 768
#define VV 256

typedef _Float16 half8 __attribute__((ext_vector_type(8)));
typedef _Float16 half4_t __attribute__((ext_vector_type(4)));
typedef float f32x4 __attribute__((ext_vector_type(4)));

// ---------------------------------------------------------------------------
// P: swizzle W_hh [256][768] and W_out [256][256] (fp32, row=K, col=N) into
// fp16 MFMA B-fragment order: flat idx = ((n_tile*8 + k_tile)*64 + lane)*8 + j
//   = n*4096 + k*512 + L*8 + j
// holding W[k_tile*32 + (lane>>4)*8 + j][n_tile*16 + (lane&15)].
// ---------------------------------------------------------------------------
__global__ __launch_bounds__(256) void swizzle_weights(
    const float* __restrict__ Whh, const float* __restrict__ Wout,
    _Float16* __restrict__ whh_swz, _Float16* __restrict__ wout_swz) {
  int t = blockIdx.x * 256 + threadIdx.x;
  if (t < 48 * 8 * 64 * 8) {  // 196608 elements of W_hh
    int j = t & 7, L = (t >> 3) & 63, k = (t >> 9) & 7, n = t >> 12;
    int row = k * 32 + (L >> 4) * 8 + j;
    int col = n * 16 + (L & 15);
    whh_swz[t] = (_Float16)Whh[row * G3 + col];
  }
  if (t < 16 * 8 * 64 * 8) {  // 65536 elements of W_out
    int j = t & 7, L = (t >> 3) & 63, k = (t >> 9) & 7, n = t >> 12;
    int row = k * 32 + (L >> 4) * 8 + j;
    int col = n * 16 + (L & 15);
    wout_swz[t] = (_Float16)Wout[row * VV + col];
  }
}

// ---------------------------------------------------------------------------
// K1: gi = emb[x] @ W_ih + b_ih (+ b_hh folded for r,z gates), written fp16 in
// the swizzled per-(batch-group, t) layout K2's lanes read with 8B loads.
// ---------------------------------------------------------------------------
__global__ __launch_bounds__(256) void gi_kernel(
    const int* __restrict__ x, const float* __restrict__ embed,
    const float* __restrict__ W_ih, const float* __restrict__ b_ih,
    const float* __restrict__ b_hh, _Float16* __restrict__ gi_swz) {
  int gid = blockIdx.x;          // 0..1023
  int bg = gid >> 7;             // batch group 0..7
  int t0 = (gid & 127) * 4;      // 4 timesteps per block
  int tid = threadIdx.x;

  __shared__ __align__(16) float s_wih[EE * G3];      // 48 KB
  __shared__ __align__(16) float s_bias[G3];          // 3 KB
  __shared__ __align__(16) float s_emb16[4][16][EE];  // 4 KB
  __shared__ int s_x[4][16];

  for (int i = tid; i < EE * G3; i += 256) s_wih[i] = W_ih[i];
  for (int i = tid; i < G3; i += 256)
    s_bias[i] = b_ih[i] + (i < 512 ? b_hh[i] : 0.0f);  // fold b_hh for r,z only
  if (tid < 64) {
    int tt = tid >> 4, m = tid & 15;
    s_x[tt][m] = x[(bg * 16 + m) * SS + t0 + tt];
  }
  __syncthreads();
  for (int i = tid; i < 4 * 16 * EE; i += 256) {
    int tt = i >> 8, m = (i >> 4) & 15, e = i & 15;
    s_emb16[tt][m][e] = embed[s_x[tt][m] * EE + e];
  }
  __syncthreads();

  for (int cch = 0; cch < 3; cch++) {
    int gc = cch * 256 + tid;  // gate column
    float w[EE];
#pragma unroll
    for (int e = 0; e < EE; e++) w[e] = s_wih[e * G3 + gc];
    float bias = s_bias[gc];
    int wi = (gc >> 4) & 15, cc = gc & 15;
    int tilebase = (cch * 16 + wi) * 64;
    for (int tt = 0; tt < 4; tt++) {
      size_t gbase = (size_t)(bg * 512 + t0 + tt) * 12288;
#pragma unroll
      for (int mq = 0; mq < 4; mq++) {
        half4_t v;
#pragma unroll
        for (int r = 0; r < 4; r++) {
          int m = mq * 4 + r;
          float acc = bias;
#pragma unroll
          for (int e = 0; e < EE; e++) acc += s_emb16[tt][m][e] * w[e];
          v[r] = (_Float16)acc;
        }
        *(half4_t*)(gi_swz + gbase + (size_t)((tilebase + mq * 16 + cc) * 4)) = v;
      }
    }
  }
}

// ---------------------------------------------------------------------------
// K2: GRU recurrence. 8 blocks x 1024 threads (16 waves, 4 waves/SIMD).
// R11 (measured 1205us, no spill): wN B-fragments in LDS (128KB), wR/wZ in
// registers — broke the register cliff that sank R7-R10.
//
// R12 (this round), two pressure-NEUTRAL stall cuts on the R11 base:
//  a) __syncthreads -> "s_waitcnt lgkmcnt(0)" + raw s_barrier.
//     __syncthreads drains vmcnt(0) every step: the 4 scattered 2B h_seq
//     stores (issued late in the epilogue, ack ~300-600cy -> exposed) and
//     the gi stream. Only the LDS h-write needs barrier visibility; h_seq
//     is write-once/never-read-here and gi-load ordering is enforced by
//     the compiler's own vmcnt at the point of use. (R8 tried this but
//     bundled it with prefetch regs and spilled — confound now removed.)
//  b) hp (z-blend h_{t-1}) carried in registers: the lane's own previous
//     C-fragment, bit-identical fp16; removes 4 ds_read_u16/wave/step from
//     the lgkm drain and the LDS pipe. +2 regs only.
// Budget (measured R11): step 5647cy; VALU-class issue 4444 (incl ~1520
// MFMA), LDS pipe ~3800-4300 — co-saturated; the ~1200-1500cy gap is
// stalls, of which the vmcnt store-drain is the nameable part.
// Tripwire: WRITE_SIZE must stay EXACTLY 32768 KB (any growth = spill).
// LDS: 16.9 KB h double-buffer + 128 KB wN = 144.9 KB (<160 KB/WG).
// ---------------------------------------------------------------------------
__global__ void __launch_bounds__(1024)
__attribute__((amdgpu_waves_per_eu(4, 4)))
gru_kernel(
    const _Float16* __restrict__ gi_swz, const _Float16* __restrict__ whh_swz,
    const float* __restrict__ b_hh, _Float16* __restrict__ h_seq) {
  int bg = blockIdx.x;  // 0..7
  int tid = threadIdx.x;
  int w = tid >> 6, L = tid & 63;
  int q = L >> 4, c = L & 15;

  __shared__ __align__(16) _Float16 s_h[2][16][264];  // 16.9 KB
  __shared__ __align__(16) _Float16 s_wn[65536];      // 128 KB: n-gate B-frags

  // r,z B fragments for this wave's column tile, in registers (64 VGPR).
  half8 wR[8], wZ[8];
#pragma unroll
  for (int k = 0; k < 8; k++) {
    wR[k] = *(const half8*)(whh_swz + (((size_t)((0 * 16 + w) * 8 + k) * 64 + L) * 8));
    wZ[k] = *(const half8*)(whh_swz + (((size_t)((1 * 16 + w) * 8 + k) * 64 + L) * 8));
  }
  // n-gate hidden bias (multiplied by r inside the step)
  float bhn = b_hh[512 + w * 16 + c];

  // Stage n-gate fragments into LDS: s_wn[i] = whh_swz[131072 + i]
  // (n-gate tiles start at (2*16)*8*64*8 = 131072). 8 x half8 per thread,
  // coalesced global reads, stride-1 LDS writes.
  for (int i = tid; i < 8192; i += 1024)
    *(half8*)(s_wn + i * 8) = *(const half8*)(whh_swz + 131072 + (size_t)i * 8);

  // zero both h buffers (h0 = 0): 8448 halves = 4224 uints
  for (int idx = tid; idx < (2 * 16 * 264) / 2; idx += 1024)
    ((unsigned int*)s_h)[idx] = 0u;
  __syncthreads();

  // lane's own h_{t-1} C-fragment, register-carried (h0 = 0); bit-identical
  // to re-reading the stored fp16 from LDS.
  half4_t hp = {(_Float16)0.f, (_Float16)0.f, (_Float16)0.f, (_Float16)0.f};

  int col = w * 16 + c;
  // h_seq flat offset (halves) for (batch row bg*16 + q*4, t=0, col)
  unsigned hoff = (unsigned)(bg * 16 + q * 4) * (SS * HH) + (unsigned)col;
  // gi offset for this lane (advance by 12288/step)
  unsigned gioff = (unsigned)(bg * 512) * 12288u + (unsigned)((w * 64 + L) * 4);

  const _Float16* hsrc = &s_h[0][0][0];
  _Float16* hdst = &s_h[1][0][0];
  const int aoff = c * 264 + q * 8;             // av base (halves)
  const int woff = (q * 4) * 264 + col;         // h-write base (halves)
  const int wnoff = w * 4096 + L * 8;           // wN base for k=0 (halves)

#pragma unroll 1
  for (int t = 0; t < SS; t++) {
    // gate-input loads (global; issued early, consumed in epilogue)
    half4_t giR = *(const half4_t*)(gi_swz + gioff);
    half4_t giZ = *(const half4_t*)(gi_swz + gioff + 4096u);
    half4_t giN = *(const half4_t*)(gi_swz + gioff + 8192u);

    f32x4 aR = {0.f, 0.f, 0.f, 0.f}, aZ = aR, aN = aR;
#pragma unroll
    for (int k = 0; k < 8; k++) {
      half8 av = *(const half8*)(hsrc + aoff + k * 32);  // A[m=c][k*32+q*8+j]
      half8 wNk = *(const half8*)(s_wn + wnoff + k * 512);  // stride-1, no conflict
      aR = __builtin_amdgcn_mfma_f32_16x16x32_f16(av, wR[k], aR, 0, 0, 0);
      aZ = __builtin_amdgcn_mfma_f32_16x16x32_f16(av, wZ[k], aZ, 0, 0, 0);
      aN = __builtin_amdgcn_mfma_f32_16x16x32_f16(av, wNk, aN, 0, 0, 0);
    }

#pragma unroll
    for (int r = 0; r < 4; r++) {
      float rg = aR[r] + (float)giR[r];
      rg = 1.f / (1.f + __expf(-rg));
      float zg = aZ[r] + (float)giZ[r];
      zg = 1.f / (1.f + __expf(-zg));
      float ng = (float)giN[r] + rg * (aN[r] + bhn);
      ng = 2.f / (1.f + __expf(-2.f * ng)) - 1.f;  // tanh
      float hn = (1.f - zg) * ng + zg * (float)hp[r];
      _Float16 h16 = (_Float16)hn;
      hp[r] = h16;
      hdst[woff + r * 264] = h16;
      h_seq[(size_t)(hoff + (unsigned)r * 131072u)] = h16;
    }

    // LDS-only drain + raw barrier: h_seq stores and the gi stream stay in
    // flight across the barrier (no vmcnt(0) — the __syncthreads stall).
    asm volatile("s_waitcnt lgkmcnt(0)" ::: "memory");
    __builtin_amdgcn_s_barrier();

    const _Float16* tp = hsrc; hsrc = hdst; hdst = (_Float16*)tp;
    hoff += (unsigned)HH;
    gioff += 12288u;
  }
}

// ---------------------------------------------------------------------------
// K3: out = h_seq @ W_out + b_out via fp16 MFMA. 1024 blocks x 256 threads;
// block handles 64 bt-rows (wave w -> rows w*16..+16), full N=256 (16 tiles).
// Static LDS = 33 KB.  Output written fp32.
// ---------------------------------------------------------------------------
__global__ __launch_bounds__(256) void out_kernel(
    const _Float16* __restrict__ h_seq, const _Float16* __restrict__ wout_swz,
    const float* __restrict__ b_out, float* __restrict__ out) {
  int blk = blockIdx.x;
  int tid = threadIdx.x;
  int w = tid >> 6, L = tid & 63, q = L >> 4, c = L & 15;

  __shared__ __align__(16) _Float16 s_a[64 * 264];  // 33 KB

  const _Float16* src = h_seq + (size_t)blk * 64 * 256;
  for (int idx = tid; idx < (64 * 256) / 8; idx += 256) {
    int row = idx >> 5, kk = (idx & 31) * 8;
    *(half8*)(s_a + row * 264 + kk) = *(const half8*)(src + row * 256 + kk);
  }
  __syncthreads();

  half8 a[8];
#pragma unroll
  for (int k = 0; k < 8; k++)
    a[k] = *(const half8*)(s_a + (w * 16 + c) * 264 + k * 32 + q * 8);

  f32x4 acc[16];
#pragma unroll
  for (int n = 0; n < 16; n++) {
    f32x4 z = {0.f, 0.f, 0.f, 0.f};
    acc[n] = z;
#pragma unroll
    for (int k = 0; k < 8; k++) {
      half8 b = *(const half8*)(wout_swz + ((size_t)(n * 8 + k) * 64 + L) * 8);
      acc[n] = __builtin_amdgcn_mfma_f32_16x16x32_f16(a[k], b, acc[n], 0, 0, 0);
    }
  }
#pragma unroll
  for (int n = 0; n < 16; n++) {
    int v = n * 16 + c;
    float bo = b_out[v];
#pragma unroll
    for (int r = 0; r < 4; r++) {
      int bt = blk * 64 + w * 16 + q * 4 + r;
      out[(size_t)bt * 256 + v] = acc[n][r] + bo;
    }
  }
}

// ---------------------------------------------------------------------------
extern "C" void kernel_launch(void* const* d_in, const int* in_sizes, int n_in,
                              void* d_out, int out_size, void* d_ws, size_t ws_size,
                              hipStream_t stream) {
  const int*   x    = (const int*)d_in[0];
  const float* emb  = (const float*)d_in[1];
  const float* Wih  = (const float*)d_in[2];
  const float* bih  = (const float*)d_in[3];
  const float* Whh  = (const float*)d_in[4];
  const float* bhh  = (const float*)d_in[5];
  const float* Wout = (const float*)d_in[6];
  const float* bout = (const float*)d_in[7];

  char* ws = (char*)d_ws;
  // ws layout (134,742,016 B total):
  //   gi_swz   : 128*512*768 fp16 = 100,663,296 B
  //   whh_swz  : 196608 fp16      =     393,216 B
  //   wout_swz : 65536 fp16       =     131,072 B
  //   h_seq    : 128*512*256 fp16 =  33,554,432 B
  _Float16* gi_swz   = (_Float16*)(ws);
  _Float16* whh_swz  = (_Float16*)(ws + 100663296);
  _Float16* wout_swz = (_Float16*)(ws + 100663296 + 393216);
  _Float16* h_seq    = (_Float16*)(ws + 100663296 + 393216 + 131072);

  swizzle_weights<<<768, 256, 0, stream>>>(Whh, Wout, whh_swz, wout_swz);
  gi_kernel<<<1024, 256, 0, stream>>>(x, emb, Wih, bih, bhh, gi_swz);
  gru_kernel<<<8, 1024, 0, stream>>>(gi_swz, whh_swz, bhh, h_seq);
  out_kernel<<<1024, 256, 0, stream>>>(h_seq, wout_swz, bout, (float*)d_out);
}